// Round 2
// baseline (697.812 us; speedup 1.0000x reference)
//
#include <hip/hip_runtime.h>
#include <math.h>

#define N_COLS 4096
#define N_ROWS 16
#define N_BATCH 256
#define N_ITER 200
#define THREADS 512
#define CPT 8  // columns per thread: 512*8 = 4096

// ---------------------------------------------------------------------------
// Kernel 1: global Cmax = max over all (b, j, n) of (s - alpha_j)^2.
// For each s, max over alpha in {0..15} is attained at an endpoint (parabola),
// with margin >> fp rounding, so max(s^2, (s-15)^2) matches the reference's
// elementwise values exactly.
// ---------------------------------------------------------------------------
__global__ void cmax_kernel(const float* __restrict__ scores,
                            unsigned int* __restrict__ ws) {
    int idx = blockIdx.x * blockDim.x + threadIdx.x;
    float m = 0.0f;
    for (int i = idx; i < N_BATCH * N_COLS; i += gridDim.x * blockDim.x) {
        float s = scores[i];
        float t = s - 15.0f;
        m = fmaxf(m, fmaxf(s * s, t * t));
    }
    #pragma unroll
    for (int off = 32; off > 0; off >>= 1)
        m = fmaxf(m, __shfl_xor(m, off));
    __shared__ float sm[8];
    int lane = threadIdx.x & 63;
    int wv = threadIdx.x >> 6;
    if (lane == 0) sm[wv] = m;
    __syncthreads();
    if (threadIdx.x == 0) {
        int nw = blockDim.x >> 6;
        float mm = sm[0];
        for (int w = 1; w < nw; ++w) mm = fmaxf(mm, sm[w]);
        // all values >= 0 -> uint bit-order == float order
        atomicMax(ws, __float_as_uint(mm));
    }
}

// ---------------------------------------------------------------------------
// Kernel 2: 200 Sinkhorn iterations per batch row, in scaling (u,v) form.
//   w_n   = exp(20*invC*s_n)                      (constant over iterations)
//   S_n   = sum_j u_j * w_n^(15-j)                (Horner, 15 fma)
//   v_n   = 1 / (4096 * S_n)                      (== exp(10 f_n - 10 invC s_n^2))
//   T_j   = sum_n v_n * w_n^(15-j)                (16 fma/col + block reduce)
//   u_j   = nu_j / T_j                            (== exp(10 g_n - 10 invC a_j^2))
//   A[b,n,j] = 4096 * v_n * u_j * w_n^(15-j), j = 0..14
// ---------------------------------------------------------------------------
__global__ __launch_bounds__(THREADS, 1) void sinkhorn_kernel(
    const float* __restrict__ scores,
    const unsigned int* __restrict__ ws,
    float* __restrict__ out)
{
    const int b = blockIdx.x;
    const int t = threadIdx.x;
    const int lane = t & 63;
    const int wv = t >> 6;

    __shared__ __align__(16) float u_sh[16];
    __shared__ __align__(16) float tstage[THREADS / 64][16];

    const float cmax = __uint_as_float(ws[0]);
    const float invC = 1.0f / cmax;

    float w[CPT];
    float v[CPT];
    const float* srow = scores + b * N_COLS;
    #pragma unroll
    for (int c = 0; c < CPT; ++c) {
        float s = srow[t + THREADS * c];
        w[c] = expf(20.0f * invC * s);
    }

    if (t < 16) {
        float alpha = (float)(15 - t);
        u_sh[t] = expf(-10.0f * invC * alpha * alpha);  // g0 = 0
    }
    __syncthreads();

    for (int it = 0; it < N_ITER; ++it) {
        float u[16];
        #pragma unroll
        for (int j = 0; j < 16; ++j) u[j] = u_sh[j];

        float Tp[16];
        #pragma unroll
        for (int j = 0; j < 16; ++j) Tp[j] = 0.0f;

        #pragma unroll
        for (int c = 0; c < CPT; ++c) {
            const float wn = w[c];
            // S = u[0]*w^15 + u[1]*w^14 + ... + u[15]
            float S = u[0];
            #pragma unroll
            for (int j = 1; j < 16; ++j) S = S * wn + u[j];
            const float vn = 1.0f / (4096.0f * S);
            v[c] = vn;
            // Tp[j] += vn * w^(15-j)
            float p = vn;
            Tp[15] += p;
            #pragma unroll
            for (int j = 14; j >= 0; --j) { p *= wn; Tp[j] += p; }
        }

        // wave-level butterfly reduce of the 16 partials
        #pragma unroll
        for (int j = 0; j < 16; ++j) {
            float x = Tp[j];
            #pragma unroll
            for (int off = 32; off > 0; off >>= 1)
                x += __shfl_xor(x, off);
            Tp[j] = x;
        }
        if (lane == 0) {
            #pragma unroll
            for (int j = 0; j < 16; ++j) tstage[wv][j] = Tp[j];
        }
        __syncthreads();
        if (t < 16) {
            float T = tstage[0][t];
            #pragma unroll
            for (int x = 1; x < THREADS / 64; ++x) T += tstage[x][t];
            const float nu = (t == 15) ? (4081.0f / 4096.0f) : (1.0f / 4096.0f);
            u_sh[t] = nu / T;  // nu_j exact in f32 (4081*2^-12, 2^-12)
        }
        __syncthreads();
    }

    // epilogue: A[b,n,j] = 4096 * v_n * u_j * w_n^(15-j), j = 0..14
    float uf[15];
    #pragma unroll
    for (int j = 0; j < 15; ++j) uf[j] = u_sh[j];

    #pragma unroll
    for (int c = 0; c < CPT; ++c) {
        const int n = t + THREADS * c;
        float* o = out + ((size_t)b * N_COLS + n) * 15;
        const float wn = w[c];
        float p = 4096.0f * v[c] * wn;  // w^1 for j=14
        #pragma unroll
        for (int j = 14; j >= 0; --j) {
            o[j] = p * uf[j];
            p *= wn;
        }
    }
}

extern "C" void kernel_launch(void* const* d_in, const int* in_sizes, int n_in,
                              void* d_out, int out_size, void* d_ws, size_t ws_size,
                              hipStream_t stream) {
    const float* scores = (const float*)d_in[0];
    unsigned int* ws = (unsigned int*)d_ws;
    float* out = (float*)d_out;

    hipMemsetAsync(d_ws, 0, sizeof(unsigned int), stream);
    cmax_kernel<<<256, 256, 0, stream>>>(scores, ws);
    sinkhorn_kernel<<<N_BATCH, THREADS, 0, stream>>>(scores, ws, out);
}

// Round 3
// 450.572 us; speedup vs baseline: 1.5487x; 1.5487x over previous
//
#include <hip/hip_runtime.h>
#include <math.h>

#define N_COLS 4096
#define N_BATCH 256
#define N_ITER 200
#define THREADS 1024
#define CPT 4              // 1024 * 4 = 4096 columns
#define NWAVES (THREADS / 64)

// ---------------------------------------------------------------------------
// Kernel 1: global Cmax = max over all (b, j, n) of (s - alpha_j)^2.
// Parabola max over alpha in {0..15} is at an endpoint -> max(s^2, (s-15)^2),
// bitwise identical to the reference's elementwise C values.
// ---------------------------------------------------------------------------
__global__ void cmax_kernel(const float* __restrict__ scores,
                            unsigned int* __restrict__ ws) {
    int idx = blockIdx.x * blockDim.x + threadIdx.x;
    float m = 0.0f;
    for (int i = idx; i < N_BATCH * N_COLS; i += gridDim.x * blockDim.x) {
        float s = scores[i];
        float t = s - 15.0f;
        m = fmaxf(m, fmaxf(s * s, t * t));
    }
    #pragma unroll
    for (int off = 32; off > 0; off >>= 1)
        m = fmaxf(m, __shfl_xor(m, off));
    __shared__ float sm[4];
    if ((threadIdx.x & 63) == 0) sm[threadIdx.x >> 6] = m;
    __syncthreads();
    if (threadIdx.x == 0) {
        float mm = fmaxf(fmaxf(sm[0], sm[1]), fmaxf(sm[2], sm[3]));
        atomicMax(ws, __float_as_uint(mm));  // all >= 0: uint order == float order
    }
}

// ---------------------------------------------------------------------------
// Kernel 2: 200 Sinkhorn iterations per batch row, scaling (u,v) form.
//   w_n = exp(20*invC*s_n)  (iteration-invariant)
//   S_n = sum_j u_j w_n^(15-j)   (Horner);  v_n = 1/(4096 S_n)
//   T_j = sum_n v_n w_n^(15-j);  u_j = nu_j / T_j
//   A[b,n,j] = 4096 v_n u_j w_n^(15-j), j=0..14
// One barrier per iteration: intra-wave select-exchange halving reduce puts
// T_j at lanes with (lane>>2)&15 == j; each wave writes tstage[buf][wv][j],
// barrier, then every wave redundantly computes u and rewrites u_sh with
// bitwise-identical values (benign race; wave reads its own writes).
// tstage double-buffered so iter-i reads never collide with iter-i+2 writes.
// ---------------------------------------------------------------------------
__global__ __launch_bounds__(THREADS, 1) void sinkhorn_kernel(
    const float* __restrict__ scores,
    const unsigned int* __restrict__ ws,
    float* __restrict__ out)
{
    const int b = blockIdx.x;
    const int t = threadIdx.x;
    const int lane = t & 63;
    const int wv = t >> 6;

    __shared__ __align__(16) float u_sh[16];
    __shared__ __align__(16) float tstage[2][NWAVES][16];

    const float invC = 1.0f / __uint_as_float(ws[0]);

    float w[CPT];
    float v[CPT];
    const float* srow = scores + b * N_COLS;
    #pragma unroll
    for (int c = 0; c < CPT; ++c) {
        float s = srow[t + THREADS * c];
        w[c] = expf(20.0f * invC * s);
    }

    if (t < 16) {
        float alpha = (float)(15 - t);
        u_sh[t] = expf(-10.0f * invC * alpha * alpha);  // g0 = 0
    }
    __syncthreads();

    float u[16];
    {
        const float4* u4 = (const float4*)u_sh;
        #pragma unroll
        for (int q = 0; q < 4; ++q) {
            float4 x = u4[q];
            u[4 * q + 0] = x.x; u[4 * q + 1] = x.y;
            u[4 * q + 2] = x.z; u[4 * q + 3] = x.w;
        }
    }

    const int jown = (lane >> 2) & 15;
    const float nuown = (jown == 15) ? (4081.0f / 4096.0f) : (1.0f / 4096.0f);

    int buf = 0;
    for (int it = 0; it < N_ITER; ++it) {
        float Tp[16];
        #pragma unroll
        for (int j = 0; j < 16; ++j) Tp[j] = 0.0f;

        #pragma unroll
        for (int c = 0; c < CPT; ++c) {
            const float wn = w[c];
            float S = u[0];
            #pragma unroll
            for (int j = 1; j < 16; ++j) S = fmaf(S, wn, u[j]);
            const float vn = __builtin_amdgcn_rcpf(4096.0f * S);
            v[c] = vn;
            float p = vn;
            Tp[15] += p;
            #pragma unroll
            for (int j = 14; j >= 0; --j) { p *= wn; Tp[j] += p; }
        }

        // --- intra-wave select-exchange halving reduce: 17 shfl total ---
        float r8[8];
        {
            const bool hi = (lane & 32) != 0;
            #pragma unroll
            for (int m = 0; m < 8; ++m) {
                float keep = hi ? Tp[m + 8] : Tp[m];
                float give = hi ? Tp[m] : Tp[m + 8];
                r8[m] = keep + __shfl_xor(give, 32);
            }
        }
        float r4[4];
        {
            const bool hi = (lane & 16) != 0;
            #pragma unroll
            for (int m = 0; m < 4; ++m) {
                float keep = hi ? r8[m + 4] : r8[m];
                float give = hi ? r8[m] : r8[m + 4];
                r4[m] = keep + __shfl_xor(give, 16);
            }
        }
        float r2[2];
        {
            const bool hi = (lane & 8) != 0;
            #pragma unroll
            for (int m = 0; m < 2; ++m) {
                float keep = hi ? r4[m + 2] : r4[m];
                float give = hi ? r4[m] : r4[m + 2];
                r2[m] = keep + __shfl_xor(give, 8);
            }
        }
        float x;
        {
            const bool hi = (lane & 4) != 0;
            float keep = hi ? r2[1] : r2[0];
            float give = hi ? r2[0] : r2[1];
            x = keep + __shfl_xor(give, 4);
        }
        x += __shfl_xor(x, 2);
        x += __shfl_xor(x, 1);
        // x = wave-total of Tp[jown]

        if ((lane & 3) == 0) tstage[buf][wv][jown] = x;
        __syncthreads();

        // every lane: cross-wave sum for its own j (broadcast reads, no conflict)
        float T0 = 0.0f, T1 = 0.0f;
        #pragma unroll
        for (int wq = 0; wq < NWAVES; wq += 2) {
            T0 += tstage[buf][wq][jown];
            T1 += tstage[buf][wq + 1][jown];
        }
        const float uown = nuown * __builtin_amdgcn_rcpf(T0 + T1);
        if ((lane & 3) == 0) u_sh[jown] = uown;  // wave writes all 16 entries

        // read back our own wave's writes (same-wave DS ordering)
        {
            const float4* u4 = (const float4*)u_sh;
            #pragma unroll
            for (int q = 0; q < 4; ++q) {
                float4 xx = u4[q];
                u[4 * q + 0] = xx.x; u[4 * q + 1] = xx.y;
                u[4 * q + 2] = xx.z; u[4 * q + 3] = xx.w;
            }
        }
        buf ^= 1;
    }

    // epilogue: A[b,n,j] = 4096 * v_n * u_j * w_n^(15-j), j = 0..14
    #pragma unroll
    for (int c = 0; c < CPT; ++c) {
        const int n = t + THREADS * c;
        float* o = out + ((size_t)b * N_COLS + n) * 15;
        const float wn = w[c];
        float p = 4096.0f * v[c] * wn;  // w^1 for j=14
        #pragma unroll
        for (int j = 14; j >= 0; --j) {
            o[j] = p * u[j];
            p *= wn;
        }
    }
}

extern "C" void kernel_launch(void* const* d_in, const int* in_sizes, int n_in,
                              void* d_out, int out_size, void* d_ws, size_t ws_size,
                              hipStream_t stream) {
    const float* scores = (const float*)d_in[0];
    unsigned int* ws = (unsigned int*)d_ws;
    float* out = (float*)d_out;

    hipMemsetAsync(d_ws, 0, sizeof(unsigned int), stream);
    cmax_kernel<<<256, 256, 0, stream>>>(scores, ws);
    sinkhorn_kernel<<<N_BATCH, THREADS, 0, stream>>>(scores, ws, out);
}

// Round 7
// 402.991 us; speedup vs baseline: 1.7316x; 1.1181x over previous
//
#include <hip/hip_runtime.h>
#include <math.h>

#define N_COLS 4096
#define N_BATCH 256
#define N_ITER 200
#define THREADS 1024
#define CPT 4              // 1024 * 4 = 4096 columns
#define NWAVES (THREADS / 64)

// ---------------------------------------------------------------------------
// Kernel 1: global Cmax = max(s^2, (s-15)^2) over all elements (parabola max
// over anchors is at an endpoint) — bitwise identical to reference C values.
// ---------------------------------------------------------------------------
__global__ void cmax_kernel(const float* __restrict__ scores,
                            unsigned int* __restrict__ ws) {
    int idx = blockIdx.x * blockDim.x + threadIdx.x;
    float m = 0.0f;
    for (int i = idx; i < N_BATCH * N_COLS; i += gridDim.x * blockDim.x) {
        float s = scores[i];
        float t = s - 15.0f;
        m = fmaxf(m, fmaxf(s * s, t * t));
    }
    #pragma unroll
    for (int off = 32; off > 0; off >>= 1)
        m = fmaxf(m, __shfl_xor(m, off));
    __shared__ float sm[4];
    if ((threadIdx.x & 63) == 0) sm[threadIdx.x >> 6] = m;
    __syncthreads();
    if (threadIdx.x == 0) {
        float mm = fmaxf(fmaxf(sm[0], sm[1]), fmaxf(sm[2], sm[3]));
        atomicMax(ws, __float_as_uint(mm));  // all >= 0: uint order == float order
    }
}

// ---------------------------------------------------------------------------
// Kernel 2: 200 Sinkhorn iterations, scaling form with precomputed powers.
//   w = exp(20*invC*s); wp[k] = w^(k+1), k=0..7   (iteration-invariant)
//   S_n = sum_j u_j w^(15-j)  (Estrin: Slo + Shi*w^8, 16 FMA)
//   vn  = rcp(S)              (4096 folded away: nu' = {1,...,4081})
//   T_j = sum_n vn w^(15-j)   (16 FMA via q = vn*w^8)
//   u_j = nu'_j / T_j
//   A[b,n,j] = vn * u_j * w^(15-j), j=0..14
// Cross-lane skeleton is the round-3 HW-proven one: select-exchange shfl
// reduce (T_j lands at lanes with (lane>>2)&15 == j), double-buffered tstage,
// one barrier/iter, u broadcast via u_sh with same-wave read-back.
// ---------------------------------------------------------------------------
__global__ __launch_bounds__(THREADS, 1) void sinkhorn_kernel(
    const float* __restrict__ scores,
    const unsigned int* __restrict__ ws,
    float* __restrict__ out)
{
    const int b = blockIdx.x;
    const int t = threadIdx.x;
    const int lane = t & 63;
    const int wv = t >> 6;

    __shared__ __align__(16) float u_sh[16];
    __shared__ __align__(16) float tstage[2][NWAVES][16];

    const float invC = 1.0f / __uint_as_float(ws[0]);

    // iteration-invariant powers w^1..w^8 per column
    float wp[CPT][8];
    float v[CPT];
    const float* srow = scores + b * N_COLS;
    #pragma unroll
    for (int c = 0; c < CPT; ++c) {
        float s = srow[t + THREADS * c];
        float w = expf(20.0f * invC * s);
        wp[c][0] = w;
        #pragma unroll
        for (int k = 1; k < 8; ++k) wp[c][k] = wp[c][k - 1] * w;
    }

    // initial u_j = exp(-10*invC*(15-j)^2)  (g0 = 0), uniform across lanes
    float u[16];
    #pragma unroll
    for (int j = 0; j < 16; ++j) {
        float a = (float)((15 - j) * (15 - j));
        u[j] = expf(-10.0f * invC * a);
    }

    const int jown = (lane >> 2) & 15;                    // HW-verified mapping (round 3)
    const float nuown = (jown == 15) ? 4081.0f : 1.0f;

    int buf = 0;
    for (int it = 0; it < N_ITER; ++it) {
        float Tp[16];
        #pragma unroll
        for (int c = 0; c < CPT; ++c) {
            // S = sum_j u[j] * w^(15-j), Estrin split at w^8
            float Slo = u[15];
            float Shi = u[7];
            #pragma unroll
            for (int k = 1; k < 8; ++k) {
                Slo = fmaf(u[15 - k], wp[c][k - 1], Slo);
                Shi = fmaf(u[7 - k], wp[c][k - 1], Shi);
            }
            const float S = fmaf(Shi, wp[c][7], Slo);
            const float vn = __builtin_amdgcn_rcpf(S);
            v[c] = vn;
            const float q = vn * wp[c][7];  // vn * w^8
            if (c == 0) {
                Tp[15] = vn;
                Tp[7] = q;
                #pragma unroll
                for (int k = 1; k < 8; ++k) {
                    Tp[15 - k] = vn * wp[c][k - 1];   // exponents 1..7
                    Tp[7 - k]  = q * wp[c][k - 1];    // exponents 9..15
                }
            } else {
                Tp[15] += vn;
                Tp[7] += q;
                #pragma unroll
                for (int k = 1; k < 8; ++k) {
                    Tp[15 - k] = fmaf(vn, wp[c][k - 1], Tp[15 - k]);
                    Tp[7 - k]  = fmaf(q, wp[c][k - 1], Tp[7 - k]);
                }
            }
        }

        // --- round-3 proven intra-wave select-exchange reduce: 17 shfl ---
        float r8[8];
        {
            const bool hi = (lane & 32) != 0;
            #pragma unroll
            for (int m = 0; m < 8; ++m) {
                float keep = hi ? Tp[m + 8] : Tp[m];
                float give = hi ? Tp[m] : Tp[m + 8];
                r8[m] = keep + __shfl_xor(give, 32);
            }
        }
        float r4[4];
        {
            const bool hi = (lane & 16) != 0;
            #pragma unroll
            for (int m = 0; m < 4; ++m) {
                float keep = hi ? r8[m + 4] : r8[m];
                float give = hi ? r8[m] : r8[m + 4];
                r4[m] = keep + __shfl_xor(give, 16);
            }
        }
        float r2[2];
        {
            const bool hi = (lane & 8) != 0;
            #pragma unroll
            for (int m = 0; m < 2; ++m) {
                float keep = hi ? r4[m + 2] : r4[m];
                float give = hi ? r4[m] : r4[m + 2];
                r2[m] = keep + __shfl_xor(give, 8);
            }
        }
        float x;
        {
            const bool hi = (lane & 4) != 0;
            float keep = hi ? r2[1] : r2[0];
            float give = hi ? r2[0] : r2[1];
            x = keep + __shfl_xor(give, 4);
        }
        x += __shfl_xor(x, 2);
        x += __shfl_xor(x, 1);
        // x = wave-total of Tp[jown]

        if ((lane & 3) == 0) tstage[buf][wv][jown] = x;
        __syncthreads();

        // every lane: cross-wave sum for its own j (broadcast reads, no conflict)
        float T0 = 0.0f, T1 = 0.0f;
        #pragma unroll
        for (int wq = 0; wq < NWAVES; wq += 2) {
            T0 += tstage[buf][wq][jown];
            T1 += tstage[buf][wq + 1][jown];
        }
        const float uown = nuown * __builtin_amdgcn_rcpf(T0 + T1);
        if ((lane & 3) == 0) u_sh[jown] = uown;  // wave writes all 16 entries

        // read back our own wave's writes (same-wave DS ordering; values are
        // bitwise identical across waves -> benign race, proven round 3)
        {
            const float4* u4 = (const float4*)u_sh;
            #pragma unroll
            for (int q4 = 0; q4 < 4; ++q4) {
                float4 xx = u4[q4];
                u[4 * q4 + 0] = xx.x; u[4 * q4 + 1] = xx.y;
                u[4 * q4 + 2] = xx.z; u[4 * q4 + 3] = xx.w;
            }
        }
        buf ^= 1;
    }

    // epilogue: A[b,n,j] = vn * u_j * w^(15-j), j = 0..14
    #pragma unroll
    for (int c = 0; c < CPT; ++c) {
        const int n = t + THREADS * c;
        float* o = out + ((size_t)b * N_COLS + n) * 15;
        const float vn = v[c];
        const float q = vn * wp[c][7];               // vn * w^8
        #pragma unroll
        for (int j = 0; j < 7; ++j) o[j] = q * wp[c][6 - j] * u[j];    // w^15..w^9
        o[7] = q * u[7];                                               // w^8
        #pragma unroll
        for (int j = 8; j < 15; ++j) o[j] = vn * wp[c][14 - j] * u[j]; // w^7..w^1
    }
}

extern "C" void kernel_launch(void* const* d_in, const int* in_sizes, int n_in,
                              void* d_out, int out_size, void* d_ws, size_t ws_size,
                              hipStream_t stream) {
    const float* scores = (const float*)d_in[0];
    unsigned int* ws = (unsigned int*)d_ws;
    float* out = (float*)d_out;

    hipMemsetAsync(d_ws, 0, sizeof(unsigned int), stream);
    cmax_kernel<<<256, 256, 0, stream>>>(scores, ws);
    sinkhorn_kernel<<<N_BATCH, THREADS, 0, stream>>>(scores, ws, out);
}

// Round 8
// 375.164 us; speedup vs baseline: 1.8600x; 1.0742x over previous
//
#include <hip/hip_runtime.h>
#include <math.h>

#define N_COLS 4096
#define N_BATCH 256
#define N_ITER 200
#define THREADS 1024
#define CPT 4              // 1024 * 4 = 4096 columns
#define NWAVES (THREADS / 64)

typedef float f32x2 __attribute__((ext_vector_type(2)));

// ---------------------------------------------------------------------------
// Kernel 1: global Cmax = max(s^2, (s-15)^2) over all elements (parabola max
// over anchors is at an endpoint) — bitwise identical to reference C values.
// ---------------------------------------------------------------------------
__global__ void cmax_kernel(const float* __restrict__ scores,
                            unsigned int* __restrict__ ws) {
    int idx = blockIdx.x * blockDim.x + threadIdx.x;
    float m = 0.0f;
    for (int i = idx; i < N_BATCH * N_COLS; i += gridDim.x * blockDim.x) {
        float s = scores[i];
        float t = s - 15.0f;
        m = fmaxf(m, fmaxf(s * s, t * t));
    }
    #pragma unroll
    for (int off = 32; off > 0; off >>= 1)
        m = fmaxf(m, __shfl_xor(m, off));
    __shared__ float sm[4];
    if ((threadIdx.x & 63) == 0) sm[threadIdx.x >> 6] = m;
    __syncthreads();
    if (threadIdx.x == 0) {
        float mm = fmaxf(fmaxf(sm[0], sm[1]), fmaxf(sm[2], sm[3]));
        atomicMax(ws, __float_as_uint(mm));  // all >= 0: uint order == float order
    }
}

// ---------------------------------------------------------------------------
// Kernel 2: 200 Sinkhorn iterations, scaling form, packed-f32 arithmetic.
//   wps[c][k] = (w^(k+1), w^(k+1))  splatted, iteration-invariant
//   up[k]     = (u[15-k], u[7-k])   packed Estrin pairs (LDS kept in this
//                                    layout so float4 read-back needs no movs)
//   S = Sv.x + Sv.y*w^8 where Sv accumulates via v_pk_fma_f32
//   Tpp[k] = (Tp[15-k], Tp[7-k])   accumulated via v_pk_fma_f32
// Cross-lane skeleton unchanged from round 3/7 (HW-proven): select-exchange
// shfl reduce, double-buffered tstage, one barrier/iter, LDS u broadcast.
// Per-element math identical & same order -> bitwise-equal output to round 7.
// ---------------------------------------------------------------------------
__global__ __launch_bounds__(THREADS, 1) void sinkhorn_kernel(
    const float* __restrict__ scores,
    const unsigned int* __restrict__ ws,
    float* __restrict__ out)
{
    const int b = blockIdx.x;
    const int t = threadIdx.x;
    const int lane = t & 63;
    const int wv = t >> 6;

    __shared__ __align__(16) f32x2 u_sh2[8];
    __shared__ __align__(16) float tstage[2][NWAVES][16];

    const float invC = 1.0f / __uint_as_float(ws[0]);

    // iteration-invariant splatted powers (w^1..w^8) per column
    f32x2 wps[CPT][8];
    float v[CPT];
    const float* srow = scores + b * N_COLS;
    #pragma unroll
    for (int c = 0; c < CPT; ++c) {
        float s = srow[t + THREADS * c];
        float w = expf(20.0f * invC * s);
        float p = w;
        wps[c][0].x = p; wps[c][0].y = p;
        #pragma unroll
        for (int k = 1; k < 8; ++k) {
            p *= w;
            wps[c][k].x = p; wps[c][k].y = p;
        }
    }

    // initial u (g0 = 0) in packed layout: up[k] = (u[15-k], u[7-k]),
    // u[j] = exp(-10*invC*(15-j)^2)  ->  up[k] = (e^{-10 invC k^2}, e^{-10 invC (8+k)^2})
    f32x2 up[8];
    #pragma unroll
    for (int k = 0; k < 8; ++k) {
        up[k].x = expf(-10.0f * invC * (float)(k * k));
        up[k].y = expf(-10.0f * invC * (float)((8 + k) * (8 + k)));
    }

    const int jown = (lane >> 2) & 15;                    // HW-verified mapping
    const float nuown = (jown == 15) ? 4081.0f : 1.0f;
    // packed-layout float index for u_sh2 writer (see layout note above)
    const int uidx = (jown >= 8) ? (30 - 2 * jown) : (15 - 2 * jown);

    int buf = 0;
    for (int it = 0; it < N_ITER; ++it) {
        f32x2 Tpp[8];
        #pragma unroll
        for (int c = 0; c < CPT; ++c) {
            // Sv = (Slo, Shi), Estrin split at w^8 — packed FMA
            f32x2 Sv = up[0];
            #pragma unroll
            for (int k = 1; k < 8; ++k)
                Sv = __builtin_elementwise_fma(up[k], wps[c][k - 1], Sv);
            const float S = fmaf(Sv.y, wps[c][7].x, Sv.x);
            const float vn = __builtin_amdgcn_rcpf(S);
            v[c] = vn;
            f32x2 m;
            m.x = vn;
            m.y = vn * wps[c][7].x;   // q = vn * w^8
            if (c == 0) {
                Tpp[0] = m;
                #pragma unroll
                for (int k = 1; k < 8; ++k) Tpp[k] = m * wps[c][k - 1];
            } else {
                Tpp[0] += m;
                #pragma unroll
                for (int k = 1; k < 8; ++k)
                    Tpp[k] = __builtin_elementwise_fma(m, wps[c][k - 1], Tpp[k]);
            }
        }

        // --- round-3 proven intra-wave select-exchange reduce: 17 shfl ---
        // Tp[m] (j=m) = Tpp[7-m].y ; Tp[m+8] = Tpp[7-m].x
        float r8[8];
        {
            const bool hi = (lane & 32) != 0;
            #pragma unroll
            for (int m8 = 0; m8 < 8; ++m8) {
                f32x2 pr = Tpp[7 - m8];
                float keep = hi ? pr.x : pr.y;
                float give = hi ? pr.y : pr.x;
                r8[m8] = keep + __shfl_xor(give, 32);
            }
        }
        float r4[4];
        {
            const bool hi = (lane & 16) != 0;
            #pragma unroll
            for (int m4 = 0; m4 < 4; ++m4) {
                float keep = hi ? r8[m4 + 4] : r8[m4];
                float give = hi ? r8[m4] : r8[m4 + 4];
                r4[m4] = keep + __shfl_xor(give, 16);
            }
        }
        float r2[2];
        {
            const bool hi = (lane & 8) != 0;
            #pragma unroll
            for (int m2 = 0; m2 < 2; ++m2) {
                float keep = hi ? r4[m2 + 2] : r4[m2];
                float give = hi ? r4[m2] : r4[m2 + 2];
                r2[m2] = keep + __shfl_xor(give, 8);
            }
        }
        float x;
        {
            const bool hi = (lane & 4) != 0;
            float keep = hi ? r2[1] : r2[0];
            float give = hi ? r2[0] : r2[1];
            x = keep + __shfl_xor(give, 4);
        }
        x += __shfl_xor(x, 2);
        x += __shfl_xor(x, 1);
        // x = wave-total of Tp[jown]

        if ((lane & 3) == 0) tstage[buf][wv][jown] = x;
        __syncthreads();

        // every lane: cross-wave sum for its own j (broadcast reads)
        float T0 = 0.0f, T1 = 0.0f;
        #pragma unroll
        for (int wq = 0; wq < NWAVES; wq += 2) {
            T0 += tstage[buf][wq][jown];
            T1 += tstage[buf][wq + 1][jown];
        }
        const float uown = nuown * __builtin_amdgcn_rcpf(T0 + T1);
        if ((lane & 3) == 0) ((float*)u_sh2)[uidx] = uown;  // packed-layout store

        // read back our own wave's writes; float4 loads deliver up[] pairs
        {
            const float4* u4 = (const float4*)u_sh2;
            #pragma unroll
            for (int q4 = 0; q4 < 4; ++q4) {
                float4 xx = u4[q4];
                up[2 * q4 + 0].x = xx.x; up[2 * q4 + 0].y = xx.y;
                up[2 * q4 + 1].x = xx.z; up[2 * q4 + 1].y = xx.w;
            }
        }
        buf ^= 1;
    }

    // epilogue: A[b,n,j] = vn * u_j * w^(15-j), j = 0..14
    // u[j]: j<=7 -> up[7-j].y ; j>=8 -> up[15-j].x
    float uf[15];
    #pragma unroll
    for (int j = 0; j < 8; ++j) uf[j] = up[7 - j].y;
    #pragma unroll
    for (int j = 8; j < 15; ++j) uf[j] = up[15 - j].x;

    #pragma unroll
    for (int c = 0; c < CPT; ++c) {
        const int n = t + THREADS * c;
        float* o = out + ((size_t)b * N_COLS + n) * 15;
        const float vn = v[c];
        const float q = vn * wps[c][7].x;            // vn * w^8
        #pragma unroll
        for (int j = 0; j < 7; ++j) o[j] = q * wps[c][6 - j].x * uf[j];    // w^15..w^9
        o[7] = q * uf[7];                                                  // w^8
        #pragma unroll
        for (int j = 8; j < 15; ++j) o[j] = vn * wps[c][14 - j].x * uf[j]; // w^7..w^1
    }
}

extern "C" void kernel_launch(void* const* d_in, const int* in_sizes, int n_in,
                              void* d_out, int out_size, void* d_ws, size_t ws_size,
                              hipStream_t stream) {
    const float* scores = (const float*)d_in[0];
    unsigned int* ws = (unsigned int*)d_ws;
    float* out = (float*)d_out;

    hipMemsetAsync(d_ws, 0, sizeof(unsigned int), stream);
    cmax_kernel<<<256, 256, 0, stream>>>(scores, ws);
    sinkhorn_kernel<<<N_BATCH, THREADS, 0, stream>>>(scores, ws, out);
}